// Round 2
// baseline (510.276 us; speedup 1.0000x reference)
//
#include <hip/hip_runtime.h>
#include <math.h>
#include <stdint.h>

// ---------------------------------------------------------------------------
// MultiHeadAttention, softmax over HEAD axis (dim=1), bf16 MFMA pipeline.
// B=4, S=2048, DIM=1024, H=8, DH=128.
//   q = (Q WQ^T) * 1/sqrt(128)   [b,s,1024] bf16 (scale folded in epilogue)
//   k =  K WK^T                  [b,s,1024] bf16
//   vt = (V WV^T) transposed ->  [b,h,dh,s] bf16 (epilogue transpose)
//   FUSED attention (v5): since softmax is over heads, den[q,k]=sum_h e_h[q,k]
//   is elementwise-local -> no online softmax, no P materialization, QK
//   computed ONCE. One kernel: 8 waves = 8 heads, q-tile 32, KT=64.
//   Per iter: QK (32 MFMA) -> exp -> cross-wave den exchange (vectorized
//   f32x4 LDS, 2 barriers) -> P into wave-private swizzled LDS -> PV
//   (32 MFMA). ctx written in concat layout, out = ctx WO^T fp32.
// ---------------------------------------------------------------------------

typedef __attribute__((ext_vector_type(8))) __bf16 bf16x8;
typedef __attribute__((ext_vector_type(4))) __bf16 bf16x4;
typedef __attribute__((ext_vector_type(4))) float  f32x4;

__device__ __forceinline__ f32x4 mfma16(bf16x8 a, bf16x8 b, f32x4 c) {
    return __builtin_amdgcn_mfma_f32_16x16x32_bf16(a, b, c, 0, 0, 0);
}

// async global->LDS, 16B per lane; LDS dest must be wave-uniform-base + lane*16
__device__ __forceinline__ void cp16(void* lds, const void* g) {
    __builtin_amdgcn_global_load_lds(
        (__attribute__((address_space(1))) void*)(void*)(const_cast<void*>(g)),
        (__attribute__((address_space(3))) void*)lds,
        16, 0, 0);
}

// ---------------------------------------------------------------------------
// 4 weight tensors in one launch
__global__ void cast4_f32_to_bf16(const float* __restrict__ s0, __bf16* __restrict__ d0,
                                  const float* __restrict__ s1, __bf16* __restrict__ d1,
                                  const float* __restrict__ s2, __bf16* __restrict__ d2,
                                  const float* __restrict__ s3, __bf16* __restrict__ d3,
                                  int n4) {
    const float* s = (blockIdx.y == 0) ? s0 : (blockIdx.y == 1) ? s1
                    : (blockIdx.y == 2) ? s2 : s3;
    __bf16* d = (blockIdx.y == 0) ? d0 : (blockIdx.y == 1) ? d1
               : (blockIdx.y == 2) ? d2 : d3;
    int i = blockIdx.x * blockDim.x + threadIdx.x;
    const int stride = gridDim.x * blockDim.x;
    for (; i < n4; i += stride) {
        float4 f = ((const float4*)s)[i];
        bf16x4 o;
        o[0] = (__bf16)f.x; o[1] = (__bf16)f.y; o[2] = (__bf16)f.z; o[3] = (__bf16)f.w;
        ((bf16x4*)d)[i] = o;
    }
}

// Q, K, V activations in one launch (y selects tensor)
__global__ void cast3_f32_to_bf16(const float* __restrict__ s0, __bf16* __restrict__ d0,
                                  const float* __restrict__ s1, __bf16* __restrict__ d1,
                                  const float* __restrict__ s2, __bf16* __restrict__ d2,
                                  int n4) {
    const float* s = (blockIdx.y == 0) ? s0 : (blockIdx.y == 1) ? s1 : s2;
    __bf16* d = (blockIdx.y == 0) ? d0 : (blockIdx.y == 1) ? d1 : d2;
    int i = blockIdx.x * blockDim.x + threadIdx.x;
    const int stride = gridDim.x * blockDim.x;
    for (; i < n4; i += stride) {
        float4 f = ((const float4*)s)[i];
        bf16x4 o;
        o[0] = (__bf16)f.x; o[1] = (__bf16)f.y; o[2] = (__bf16)f.z; o[3] = (__bf16)f.w;
        ((bf16x4*)d)[i] = o;
    }
}

// ---------------------------------------------------------------------------
// C[8192,1024] = A[8192,1024] * Bt[1024,1024]^T   (Bt stored [N,K] row-major)
// MODE 1: f32 out, natural [m,n]  (used for the final WO projection)
template<int MODE>
__global__ __launch_bounds__(256, 2) void gemm_bt(const __bf16* __restrict__ A,
                                                  const __bf16* __restrict__ Bt,
                                                  void* __restrict__ out,
                                                  float scale)
{
    __shared__ __bf16 As[128 * 32];
    __shared__ __bf16 Bs[128 * 32];
    const int tid  = threadIdx.x;
    const int lane = tid & 63;
    const int u = lane >> 4, v = lane & 15;
    const int w = tid >> 6;
    const int wm = (w >> 1) * 64, wn = (w & 1) * 64;
    const long tM = (long)blockIdx.y * 128;
    const int  tN = blockIdx.x * 128;

    f32x4 acc[4][4];
#pragma unroll
    for (int i = 0; i < 4; ++i)
#pragma unroll
        for (int j = 0; j < 4; ++j) acc[i][j] = (f32x4){0.f, 0.f, 0.f, 0.f};

    const int c0 = tid, c1 = tid + 256;
    const int ar0 = c0 >> 2, ak0 = (c0 & 3) * 8;
    const int ar1 = c1 >> 2, ak1 = (c1 & 3) * 8;

    const __bf16* Ab = A  + tM * 1024;
    const __bf16* Bb = Bt + (long)tN * 1024;

    for (int k0 = 0; k0 < 1024; k0 += 32) {
        __syncthreads();
        cp16(&As[ar0 * 32 + ak0], Ab + (long)ar0 * 1024 + k0 + ak0);
        cp16(&As[ar1 * 32 + ak1], Ab + (long)ar1 * 1024 + k0 + ak1);
        cp16(&Bs[ar0 * 32 + ak0], Bb + (long)ar0 * 1024 + k0 + ak0);
        cp16(&Bs[ar1 * 32 + ak1], Bb + (long)ar1 * 1024 + k0 + ak1);
        __syncthreads();

        bf16x8 af[4], bfr[4];
#pragma unroll
        for (int i = 0; i < 4; ++i)
            af[i] = *(const bf16x8*)&As[(wm + i * 16 + v) * 32 + u * 8];
#pragma unroll
        for (int j = 0; j < 4; ++j)
            bfr[j] = *(const bf16x8*)&Bs[(wn + j * 16 + v) * 32 + u * 8];
#pragma unroll
        for (int i = 0; i < 4; ++i)
#pragma unroll
            for (int j = 0; j < 4; ++j)
                acc[i][j] = mfma16(af[i], bfr[j], acc[i][j]);
    }

#pragma unroll
    for (int i = 0; i < 4; ++i) {
#pragma unroll
        for (int j = 0; j < 4; ++j) {
            const long row0 = tM + wm + i * 16 + u * 4;
            const int  col  = tN + wn + j * 16 + v;
            if (MODE == 1) {
                float* o = (float*)out;
#pragma unroll
                for (int r = 0; r < 4; ++r)
                    o[(row0 + r) * 1024 + col] = acc[i][j][r];
            } else {
                __bf16* o = (__bf16*)out;
#pragma unroll
                for (int r = 0; r < 4; ++r)
                    o[(row0 + r) * 1024 + col] = (__bf16)(acc[i][j][r] * scale);
            }
        }
    }
}

// ---------------------------------------------------------------------------
// Batched Q/K/V projection: grid.z selects (A, Bt, out, mode).
// z=0: qp = (Xq WQ^T)*qscale   (natural bf16)
// z=1: kp =  Xk WK^T           (natural bf16)
// z=2: vt =  Xv WV^T           v-transposed [b,h,dh,s] bf16
__global__ __launch_bounds__(256, 2) void qkv_proj(
    const __bf16* __restrict__ xq, const __bf16* __restrict__ xk,
    const __bf16* __restrict__ xv,
    const __bf16* __restrict__ wq, const __bf16* __restrict__ wk,
    const __bf16* __restrict__ wv,
    __bf16* __restrict__ qp, __bf16* __restrict__ kp, __bf16* __restrict__ vtb,
    float qscale)
{
    __shared__ __bf16 As[128 * 32];
    __shared__ __bf16 Bs[128 * 32];
    const int z = blockIdx.z;
    const __bf16* A  = (z == 0) ? xq : (z == 1) ? xk : xv;
    const __bf16* Bt = (z == 0) ? wq : (z == 1) ? wk : wv;
    __bf16* out      = (z == 0) ? qp : (z == 1) ? kp : vtb;
    const float scale = (z == 0) ? qscale : 1.0f;

    const int tid  = threadIdx.x;
    const int lane = tid & 63;
    const int u = lane >> 4, v = lane & 15;
    const int w = tid >> 6;
    const int wm = (w >> 1) * 64, wn = (w & 1) * 64;
    const long tM = (long)blockIdx.y * 128;
    const int  tN = blockIdx.x * 128;

    f32x4 acc[4][4];
#pragma unroll
    for (int i = 0; i < 4; ++i)
#pragma unroll
        for (int j = 0; j < 4; ++j) acc[i][j] = (f32x4){0.f, 0.f, 0.f, 0.f};

    const int c0 = tid, c1 = tid + 256;
    const int ar0 = c0 >> 2, ak0 = (c0 & 3) * 8;
    const int ar1 = c1 >> 2, ak1 = (c1 & 3) * 8;

    const __bf16* Ab = A  + tM * 1024;
    const __bf16* Bb = Bt + (long)tN * 1024;

    for (int k0 = 0; k0 < 1024; k0 += 32) {
        __syncthreads();
        cp16(&As[ar0 * 32 + ak0], Ab + (long)ar0 * 1024 + k0 + ak0);
        cp16(&As[ar1 * 32 + ak1], Ab + (long)ar1 * 1024 + k0 + ak1);
        cp16(&Bs[ar0 * 32 + ak0], Bb + (long)ar0 * 1024 + k0 + ak0);
        cp16(&Bs[ar1 * 32 + ak1], Bb + (long)ar1 * 1024 + k0 + ak1);
        __syncthreads();

        bf16x8 af[4], bfr[4];
#pragma unroll
        for (int i = 0; i < 4; ++i)
            af[i] = *(const bf16x8*)&As[(wm + i * 16 + v) * 32 + u * 8];
#pragma unroll
        for (int j = 0; j < 4; ++j)
            bfr[j] = *(const bf16x8*)&Bs[(wn + j * 16 + v) * 32 + u * 8];
#pragma unroll
        for (int i = 0; i < 4; ++i)
#pragma unroll
            for (int j = 0; j < 4; ++j)
                acc[i][j] = mfma16(af[i], bfr[j], acc[i][j]);
    }

#pragma unroll
    for (int i = 0; i < 4; ++i) {
#pragma unroll
        for (int j = 0; j < 4; ++j) {
            const long row0 = tM + wm + i * 16 + u * 4;
            const int  col  = tN + wn + j * 16 + v;
            if (z < 2) {
#pragma unroll
                for (int r = 0; r < 4; ++r)
                    out[(row0 + r) * 1024 + col] = (__bf16)(acc[i][j][r] * scale);
            } else {
                const int bidx = (int)(row0 >> 11);
                const int s    = (int)(row0 & 2047);          // 4-aligned
                const int h = col >> 7, dh = col & 127;
                bf16x4 pk;
#pragma unroll
                for (int r = 0; r < 4; ++r) pk[r] = (__bf16)acc[i][j][r];
                *(bf16x4*)&out[((long)(bidx * 8 + h) * 128 + dh) * 2048 + s] = pk;
            }
        }
    }
}

// ---------------------------------------------------------------------------
// fused_attn: one kernel for QK^T -> head-softmax -> PV.
// Grid 256 blocks (64 q-tiles x 4 b, XCD-clustered so each XCD serves one b),
// 512 threads = 8 waves, wave w == head w. q-tile = 32 (2 qj), KT = 64 keys
// per iter, 32 iters over S=2048.
//
// Softmax over heads: den[q,k] = sum_h exp(s_h[q,k]) is elementwise-local.
// Per iter:
//   QK: acc[ki 0..3][qj 0..1] = K-frag x Q-frag (Q in registers, K from L2)
//   e = exp(acc)  (16x16x32 D-layout: k = ki*16+u*4+r, q = qj*16+v)
//   exchange: dbuf[w][g][lane] = e (g=ki*2+qj); barrier;
//             wave w sums group w over 8 waves, rinv -> rbuf[w]; barrier;
//             all waves read rbuf (broadcast).
//   P: bf16(e*rinv) -> wave-PRIVATE LDS Pl[w][q][k] (16B-chunk XOR swizzle,
//      no barrier: same-wave ds ops are in-order).
//   PV: ctx[dt][qj] += mfma(vt-frag, P-frag)  (vt from L2; kc=0 loads hoisted
//      above the barriers to hide latency under the exchange).
// Epilogue: ctx[b][q][h*128+dh] bf16 concat layout.
// LDS: dbuf 64K + rbuf 8K + Pl 32K = 104 KB -> 1 block/CU, 8 waves.
__global__ __launch_bounds__(512, 2) void fused_attn(
    const __bf16* __restrict__ qp, const __bf16* __restrict__ kp,
    const __bf16* __restrict__ vt, __bf16* __restrict__ ctx)
{
    __shared__ f32x4 dbuf[8][8][64];   // 64 KB  e-partials [wave][group][lane]
    __shared__ f32x4 rbuf[8][64];      // 8 KB   rinv per group [group][lane]
    __shared__ __bf16 Pl[8][32][64];   // 32 KB  wave-private P [q][k] swizzled

    const int tid  = threadIdx.x;
    const int w    = tid >> 6;          // wave == head
    const int lane = tid & 63;
    const int u = lane >> 4, v = lane & 15;

    // block -> (qt, b), clustered so XCD (bid%8) serves a single batch b
    const int g0 = blockIdx.x;
    const int xs = g0 & 7, idx = g0 >> 3;
    const int b  = xs >> 1;
    const int qt = idx * 2 + (xs & 1);
    const int q0 = qt * 32;
    const int h  = w;

    const __bf16* Qb = qp + ((long)b * 2048 + q0) * 1024 + h * 128;
    const __bf16* Kb = kp + (long)b * 2048 * 1024 + h * 128;
    const __bf16* Vb = vt + (long)(b * 8 + h) * 128 * 2048;

    // Q fragments resident in registers (32 VGPR)
    bf16x8 qf[2][4];
#pragma unroll
    for (int qj = 0; qj < 2; ++qj)
#pragma unroll
        for (int kk = 0; kk < 4; ++kk)
            qf[qj][kk] = *(const bf16x8*)&Qb[(long)(qj * 16 + v) * 1024 + kk * 32 + u * 8];

    f32x4 ctxa[8][2];
#pragma unroll
    for (int dt = 0; dt < 8; ++dt)
#pragma unroll
        for (int qj = 0; qj < 2; ++qj) ctxa[dt][qj] = (f32x4){0.f, 0.f, 0.f, 0.f};

    for (int kt = 0; kt < 2048; kt += 64) {
        // ---- QK: s^T[k][q] for this head ----
        f32x4 e[4][2];
#pragma unroll
        for (int ki = 0; ki < 4; ++ki)
#pragma unroll
            for (int qj = 0; qj < 2; ++qj) e[ki][qj] = (f32x4){0.f, 0.f, 0.f, 0.f};

#pragma unroll
        for (int ki = 0; ki < 4; ++ki) {
            bf16x8 kf[4];
#pragma unroll
            for (int kk = 0; kk < 4; ++kk)
                kf[kk] = *(const bf16x8*)&Kb[(long)(kt + ki * 16 + v) * 1024 + kk * 32 + u * 8];
#pragma unroll
            for (int qj = 0; qj < 2; ++qj)
#pragma unroll
                for (int kk = 0; kk < 4; ++kk)
                    e[ki][qj] = mfma16(kf[kk], qf[qj][kk], e[ki][qj]);
        }

        // ---- exp in place ----
#pragma unroll
        for (int ki = 0; ki < 4; ++ki)
#pragma unroll
            for (int qj = 0; qj < 2; ++qj)
#pragma unroll
                for (int r = 0; r < 4; ++r)
                    e[ki][qj][r] = __expf(e[ki][qj][r]);

        // hoist PV kc=0 vt loads: latency hides under the exchange barriers
        bf16x8 vf0[8];
#pragma unroll
        for (int dt = 0; dt < 8; ++dt)
            vf0[dt] = *(const bf16x8*)&Vb[(long)(dt * 16 + v) * 2048 + kt + u * 8];

        // ---- den exchange ----
#pragma unroll
        for (int ki = 0; ki < 4; ++ki)
#pragma unroll
            for (int qj = 0; qj < 2; ++qj)
                dbuf[w][ki * 2 + qj][lane] = e[ki][qj];
        __syncthreads();

        // wave w sums group w over all 8 waves
        f32x4 d = dbuf[0][w][lane];
#pragma unroll
        for (int wp = 1; wp < 8; ++wp) {
            f32x4 t = dbuf[wp][w][lane];
#pragma unroll
            for (int r = 0; r < 4; ++r) d[r] += t[r];
        }
        f32x4 rv;
#pragma unroll
        for (int r = 0; r < 4; ++r) rv[r] = 1.0f / d[r];
        rbuf[w][lane] = rv;
        __syncthreads();

        // ---- normalize, write P to wave-private swizzled LDS ----
#pragma unroll
        for (int ki = 0; ki < 4; ++ki)
#pragma unroll
            for (int qj = 0; qj < 2; ++qj) {
                f32x4 rr = rbuf[ki * 2 + qj][lane];
                bf16x4 o;
#pragma unroll
                for (int r = 0; r < 4; ++r) o[r] = (__bf16)(e[ki][qj][r] * rr[r]);
                const int q  = qj * 16 + v;
                const int ch = (ki * 2 + (u >> 1)) ^ (v & 7);   // 16B-chunk swizzle
                *(bf16x4*)((char*)&Pl[w][q][0] + ch * 16 + (u & 1) * 8) = o;
            }

        // ---- PV (wave-private Pl: same-wave ds ordering, no barrier) ----
        bf16x8 pfr[2][2];
#pragma unroll
        for (int kc = 0; kc < 2; ++kc)
#pragma unroll
            for (int qj = 0; qj < 2; ++qj) {
                const int q  = qj * 16 + v;
                const int ch = (kc * 4 + u) ^ (v & 7);
                pfr[kc][qj] = *(const bf16x8*)((const char*)&Pl[w][q][0] + ch * 16);
            }
#pragma unroll
        for (int dt = 0; dt < 8; ++dt) {
#pragma unroll
            for (int qj = 0; qj < 2; ++qj)
                ctxa[dt][qj] = mfma16(vf0[dt], pfr[0][qj], ctxa[dt][qj]);
            bf16x8 vf1 = *(const bf16x8*)&Vb[(long)(dt * 16 + v) * 2048 + kt + 32 + u * 8];
#pragma unroll
            for (int qj = 0; qj < 2; ++qj)
                ctxa[dt][qj] = mfma16(vf1, pfr[1][qj], ctxa[dt][qj]);
        }
    }

    // ---- epilogue: concat layout [b][q][h*128+dh] ----
#pragma unroll
    for (int dt = 0; dt < 8; ++dt)
#pragma unroll
        for (int qj = 0; qj < 2; ++qj) {
            bf16x4 o;
#pragma unroll
            for (int r = 0; r < 4; ++r) o[r] = (__bf16)ctxa[dt][qj][r];
            *(bf16x4*)&ctx[((long)b * 2048 + q0 + qj * 16 + v) * 1024
                           + h * 128 + dt * 16 + u * 4] = o;
        }
}

// ---------------------------------------------------------------------------
extern "C" void kernel_launch(void* const* d_in, const int* in_sizes, int n_in,
                              void* d_out, int out_size, void* d_ws, size_t ws_size,
                              hipStream_t stream)
{
    const float* Q  = (const float*)d_in[0];
    const float* K  = (const float*)d_in[1];
    const float* V  = (const float*)d_in[2];
    const float* WQ = (const float*)d_in[3];
    const float* WK = (const float*)d_in[4];
    const float* WV = (const float*)d_in[5];
    const float* WO = (const float*)d_in[6];

    // workspace layout (bf16 elems): 4x 1M weights + 7x 8.4M tensors = 125.8 MB
    __bf16* ws = (__bf16*)d_ws;
    __bf16* wq = ws;
    __bf16* wk = wq + 1048576;
    __bf16* wv = wk + 1048576;
    __bf16* wo = wv + 1048576;
    __bf16* xq = wo + 1048576;     // Q cast
    __bf16* xk = xq + 8388608;     // K cast
    __bf16* xv = xk + 8388608;     // V cast
    __bf16* qp = xv + 8388608;
    __bf16* kp = qp + 8388608;
    __bf16* vt = kp + 8388608;
    __bf16* xb = vt + 8388608;     // ctx

    const float qscale = 0.08838834764831845f;   // 1/sqrt(128)

    cast4_f32_to_bf16<<<dim3(256, 4), 256, 0, stream>>>(
        WQ, wq, WK, wk, WV, wv, WO, wo, 262144);
    cast3_f32_to_bf16<<<dim3(2048, 3), 256, 0, stream>>>(
        Q, xq, K, xk, V, xv, 2097152);
    qkv_proj<<<dim3(8, 64, 3), 256, 0, stream>>>(
        xq, xk, xv, wq, wk, wv, qp, kp, vt, qscale);

    fused_attn<<<256, 512, 0, stream>>>(qp, kp, vt, xb);

    gemm_bt<1><<<dim3(8, 64), 256, 0, stream>>>(xb, wo, (float*)d_out, 1.0f);
}